// Round 8
// baseline (306.988 us; speedup 1.0000x reference)
//
#include <hip/hip_runtime.h>

using f32x4  = __attribute__((ext_vector_type(4))) float;
using i32x4  = __attribute__((ext_vector_type(4))) int;
using i32x16 = __attribute__((ext_vector_type(16))) int;

constexpr int K_DIM = 4096;   // N_IN
constexpr int N_DIM = 4096;   // N_OUT
constexpr float QBf = 128.0f;
constexpr float EPf = 0.01f;
constexpr float LN_EPSf = 1e-5f;

#define GLOAD_LDS16(gp, lp)                                                  \
    __builtin_amdgcn_global_load_lds(                                        \
        (const __attribute__((address_space(1))) void*)(gp),                 \
        (__attribute__((address_space(3))) void*)(lp), 16, 0, 0)

#define BARRIER()                                                            \
    do { asm volatile("" ::: "memory");                                      \
         __builtin_amdgcn_s_barrier();                                       \
         asm volatile("" ::: "memory"); } while (0)

#define WAIT_LGKM(N)                                                         \
    do { asm volatile("s_waitcnt lgkmcnt(" #N ")" ::: "memory");             \
         __builtin_amdgcn_sched_barrier(0); } while (0)

#define FENCE() __builtin_amdgcn_sched_barrier(0)

// ---------------------------------------------------------------------------
// Kernel 1: fused LayerNorm + ABSMax-quant + round-to-int8.  One block/row.
// ---------------------------------------------------------------------------
__global__ __launch_bounds__(256) void ln_quant_kernel(
    const float* __restrict__ x,
    const float* __restrict__ ln_g,
    const float* __restrict__ ln_b,
    const float* __restrict__ gamma_p,
    char* __restrict__ xq)
{
    const int row = blockIdx.x;
    const int t = threadIdx.x;
    const float4* xr4 = reinterpret_cast<const float4*>(x + (size_t)row * K_DIM);

    float4 v[4];
    float sum = 0.f, sumsq = 0.f;
#pragma unroll
    for (int i = 0; i < 4; ++i) {
        v[i] = xr4[t * 4 + i];
        sum += v[i].x + v[i].y + v[i].z + v[i].w;
        sumsq += v[i].x * v[i].x + v[i].y * v[i].y + v[i].z * v[i].z + v[i].w * v[i].w;
    }
#pragma unroll
    for (int off = 32; off > 0; off >>= 1) {
        sum += __shfl_down(sum, off);
        sumsq += __shfl_down(sumsq, off);
    }
    __shared__ float s_sum[4], s_sq[4];
    const int lane = t & 63, w = t >> 6;
    if (lane == 0) { s_sum[w] = sum; s_sq[w] = sumsq; }
    __syncthreads();
    sum = s_sum[0] + s_sum[1] + s_sum[2] + s_sum[3];
    sumsq = s_sq[0] + s_sq[1] + s_sq[2] + s_sq[3];

    const float mu = sum * (1.0f / K_DIM);
    const float var = sumsq * (1.0f / K_DIM) - mu * mu;
    const float rstd = rsqrtf(var + LN_EPSf);
    const float qs = QBf / gamma_p[0];
    const float lo = -QBf + EPf, hi = QBf - EPf;

    alignas(16) char ob[16];
#pragma unroll
    for (int i = 0; i < 4; ++i) {
        const float4 g = reinterpret_cast<const float4*>(ln_g)[t * 4 + i];
        const float4 b = reinterpret_cast<const float4*>(ln_b)[t * 4 + i];
        const float f0 = fminf(fmaxf(((v[i].x - mu) * rstd * g.x + b.x) * qs, lo), hi);
        const float f1 = fminf(fmaxf(((v[i].y - mu) * rstd * g.y + b.y) * qs, lo), hi);
        const float f2 = fminf(fmaxf(((v[i].z - mu) * rstd * g.z + b.z) * qs, lo), hi);
        const float f3 = fminf(fmaxf(((v[i].w - mu) * rstd * g.w + b.w) * qs, lo), hi);
        int x0 = (int)rintf(f0), x1 = (int)rintf(f1);
        int x2 = (int)rintf(f2), x3 = (int)rintf(f3);
        ob[i * 4 + 0] = (char)(x0 > 127 ? 127 : x0);
        ob[i * 4 + 1] = (char)(x1 > 127 ? 127 : x1);
        ob[i * 4 + 2] = (char)(x2 > 127 ? 127 : x2);
        ob[i * 4 + 3] = (char)(x3 > 127 ? 127 : x3);
    }
    *reinterpret_cast<uint4*>(xq + (size_t)row * K_DIM + t * 16) =
        *reinterpret_cast<const uint4*>(ob);
}

// ---------------------------------------------------------------------------
// Kernel 2: w (fp32, K x N, values ±1) -> wq (int8, N x K).  64x64 tiles.
// ---------------------------------------------------------------------------
__global__ __launch_bounds__(256) void wtrans_kernel(
    const float* __restrict__ w, char* __restrict__ wq)
{
    __shared__ char tile[64][68];
    const int t = threadIdx.x;
    const int bk = blockIdx.y * 64;
    const int bn = blockIdx.x * 64;
#pragma unroll
    for (int i = 0; i < 4; ++i) {
        const int li = i * 1024 + t * 4;
        const int r = li >> 6, c = li & 63;    // r = k-in-tile, c = n-in-tile
        const float4 vv = *reinterpret_cast<const float4*>(
            w + (size_t)(bk + r) * N_DIM + bn + c);
        tile[r][c]     = (char)vv.x;
        tile[r][c + 1] = (char)vv.y;
        tile[r][c + 2] = (char)vv.z;
        tile[r][c + 3] = (char)vv.w;
    }
    __syncthreads();
    const int n = t >> 2, kc = t & 3;
    alignas(16) char h16[16];
#pragma unroll
    for (int j = 0; j < 16; ++j) h16[j] = tile[kc * 16 + j][n];
    *reinterpret_cast<uint4*>(wq + (size_t)(bn + n) * K_DIM + bk + kc * 16) =
        *reinterpret_cast<const uint4*>(h16);
}

// ---------------------------------------------------------------------------
// Kernel 3: GEMM  C[M,N] = A[M,K] * Bt[N,K]^T * scale  (i8 MFMA, i32 acc)
// 128x256 tile, BK=64, 256 threads = 4 waves (2M x 2N), wave tile 64x128
// (2 m-frags x 4 n-frags of mfma_i32_32x32x32_i8, 2 k-steps per K-tile).
// TWO blocks co-resident per CU (LDS 48K, VGPR <256 via launch_bounds) --
// independent blocks cover each other's barrier/latency stalls.
// LDS K-block layout [kc][row][16B] per region: fragment reads are 512
// contiguous bytes per 32-lane group -> zero bank conflicts, linear dest.
// Per K-tile (buf h = t&1), 2 barriers, counted waits (ring from R7):
//   R0: read B(ks0)x4 + A(ks0)x2 | fence | read B(ks1)x4 | fence
//   s0: read A(ks1)x2 | STAGE_A(t+1)->buf^1 | lgkm(8) | MFMA ks0,nf01
//   s1: lgkm(2) [all B done]     | MFMA ks0,nf23 | BARRIER#1
//   s2: STAGE_B(t+2)->buf h      | lgkm(0) | MFMA ks1,nf01
//   s3: MFMA ks1,nf23 | vmcnt(4) | BARRIER#2
// vmcnt(4) at s3 forces A(t+1)+B(t+1) landed, leaves B(t+2)'s 4 in flight.
// ---------------------------------------------------------------------------
__global__ __launch_bounds__(256, 2) void gemm_kernel(
    const char* __restrict__ A,
    const char* __restrict__ Bt,
    float* __restrict__ C,
    const float* __restrict__ beta_p,
    const float* __restrict__ gamma_p)
{
    constexpr int NT = K_DIM / 64;                 // 64 K-tiles
    constexpr int BUF = 24576;                     // A 8K + B 16K per buffer
    __shared__ __align__(16) char lds[2 * BUF];

    const int t = threadIdx.x;
    // ---- XCD swizzle: 1024 blocks; xcd = flat&7 owns a 16bx x 8by region
    const int flat = blockIdx.y * gridDim.x + blockIdx.x;
    const int xcd = flat & 7;
    const int r = flat >> 3;                        // 0..127
    const int bx = r & 15;                          // N index 0..15
    const int by = xcd * 8 + (r >> 4);              // M index 0..63
    const int bm = by * 128;
    const int bn = bx * 256;

    const int lane = t & 63;
    const int w = t >> 6;             // 0..3
    const int wm = w >> 1;            // 0..1  (m offset wm*64)
    const int wn = w & 1;             // 0..1  (n offset wn*128)
    const int ln31 = lane & 31;
    const int lg2 = lane >> 5;        // 0..1

    const char* gA = A + (size_t)bm * K_DIM;
    const char* gB = Bt + (size_t)bn * K_DIM;

    // frag read offsets: kc-plane = ks*2+lg2 (A stride 2048, B stride 4096)
    const int aoff = lg2 * 2048 + (wm * 64 + ln31) * 16;
    const int boff = lg2 * 4096 + (wn * 128 + ln31) * 16;

    // staging source offsets
    const int voffA = (t & 127) * K_DIM + (t >> 7) * 16;   // + kt*64 (+32 rnd1)
    const int voffB = t * K_DIM;                            // + kt*64 + r*16

#define STAGE_A(b, kt)                                                        \
    do {                                                                      \
        GLOAD_LDS16(gA + (size_t)(kt) * 64 + voffA,                           \
                    lds + (b) * BUF + t * 16);                                \
        GLOAD_LDS16(gA + (size_t)(kt) * 64 + voffA + 32,                      \
                    lds + (b) * BUF + 4096 + t * 16);                         \
    } while (0)

#define STAGE_B(b, kt)                                                        \
    do {                                                                      \
        _Pragma("unroll")                                                     \
        for (int rr = 0; rr < 4; ++rr)                                        \
            GLOAD_LDS16(gB + (size_t)(kt) * 64 + voffB + rr * 16,             \
                        lds + (b) * BUF + 8192 + rr * 4096 + t * 16);         \
    } while (0)

#define LD(p) (*reinterpret_cast<const i32x4*>(p))

#define MFMA4(ks, nfp)                                                        \
    do {                                                                      \
        __builtin_amdgcn_s_setprio(1);                                        \
        _Pragma("unroll")                                                     \
        for (int m2 = 0; m2 < 2; ++m2)                                        \
            _Pragma("unroll")                                                 \
            for (int n2 = 0; n2 < 2; ++n2)                                    \
                acc[m2][(nfp) * 2 + n2] =                                     \
                    __builtin_amdgcn_mfma_i32_32x32x32_i8(                    \
                        afr[ks][m2], bfr[(nfp) * 2 + n2][ks],                 \
                        acc[m2][(nfp) * 2 + n2], 0, 0, 0);                    \
        __builtin_amdgcn_s_setprio(0);                                        \
    } while (0)

    i32x16 acc[2][4];
#pragma unroll
    for (int m = 0; m < 2; ++m)
#pragma unroll
        for (int n = 0; n < 4; ++n)
#pragma unroll
            for (int q = 0; q < 16; ++q)
                acc[m][n][q] = 0;

    // prologue: A(0),B(0) -> buf0; B(1) -> buf1; force A(0),B(0); sync
    STAGE_A(0, 0); STAGE_B(0, 0); STAGE_B(1, 1);
    asm volatile("s_waitcnt vmcnt(4)" ::: "memory");
    BARRIER();

    for (int kt = 0; kt < NT; kt += 2) {
#pragma unroll
        for (int h = 0; h < 2; ++h) {
            const int tt = kt + h;                         // current K-tile
            const char* ab = lds + h * BUF;                // A region
            const char* bb = lds + h * BUF + 8192;         // B region

            i32x4 bfr[4][2];   // [nf][ks]
            i32x4 afr[2][2];   // [ks][m2]

            // ---- R0 group 1: B(ks0) nf0,1 + A(ks0) (needed at s0) ----
            bfr[0][0] = LD(bb + boff);
            bfr[1][0] = LD(bb + boff + 512);
            afr[0][0] = LD(ab + aoff);
            afr[0][1] = LD(ab + aoff + 512);
            FENCE();
            // ---- R0 group 2: B(ks0) nf2,3 + B(ks1) all ----
            bfr[2][0] = LD(bb + boff + 1024);
            bfr[3][0] = LD(bb + boff + 1536);
            bfr[0][1] = LD(bb + boff + 8192);
            bfr[1][1] = LD(bb + boff + 8192 + 512);
            bfr[2][1] = LD(bb + boff + 8192 + 1024);
            bfr[3][1] = LD(bb + boff + 8192 + 1536);
            FENCE();

            // ---- s0: read-ahead A(ks1); stage A(t+1) ----
            afr[1][0] = LD(ab + 4096 + aoff);
            afr[1][1] = LD(ab + 4096 + aoff + 512);
            if (tt + 1 < NT) STAGE_A(h ^ 1, tt + 1);
            WAIT_LGKM(8);                 // group-1 reads done
            MFMA4(0, 0);

            // ---- s1 ----
            WAIT_LGKM(2);                 // ALL B reads done (A ks1 may fly)
            MFMA4(0, 1);
            BARRIER();                    // B(t) slots reusable chip-wide

            // ---- s2: stage B(t+2) into freed slots ----
            if (tt + 2 < NT) STAGE_B(h, tt + 2);
            WAIT_LGKM(0);                 // A(ks1) done
            MFMA4(1, 0);

            // ---- s3 ----
            MFMA4(1, 1);
            if (tt + 2 < NT) asm volatile("s_waitcnt vmcnt(4)" ::: "memory");
            else             asm volatile("s_waitcnt vmcnt(0)" ::: "memory");
            BARRIER();                    // next tile fully staged
        }
    }

    // ---- epilogue: 32x32 C/D layout: col=lane&31,
    //      row = (reg&3) + 8*(reg>>2) + 4*(lane>>5) ----
    const float scale = beta_p[0] * gamma_p[0] * (1.0f / QBf);
    const int orow0 = bm + wm * 64 + lg2 * 4;
    const int ocol0 = bn + wn * 128 + ln31;
#pragma unroll
    for (int m2 = 0; m2 < 2; ++m2) {
#pragma unroll
        for (int nf = 0; nf < 4; ++nf) {
#pragma unroll
            for (int reg = 0; reg < 16; ++reg) {
                const int row = orow0 + m2 * 32 + (reg & 3) + 8 * (reg >> 2);
                C[(size_t)row * N_DIM + ocol0 + nf * 32] =
                    (float)acc[m2][nf][reg] * scale;
            }
        }
    }
#undef STAGE_A
#undef STAGE_B
#undef LD
#undef MFMA4
}

// ---------------------------------------------------------------------------
extern "C" void kernel_launch(void* const* d_in, const int* in_sizes, int n_in,
                              void* d_out, int out_size, void* d_ws, size_t ws_size,
                              hipStream_t stream)
{
    const float* x       = (const float*)d_in[0];
    const float* w       = (const float*)d_in[1];
    const float* ln_g    = (const float*)d_in[2];
    const float* ln_b    = (const float*)d_in[3];
    const float* beta_p  = (const float*)d_in[4];
    const float* gamma_p = (const float*)d_in[5];
    float* out = (float*)d_out;

    const int M = in_sizes[0] / K_DIM;   // 8192

    char* xq = (char*)d_ws;
    char* wq = (char*)d_ws + (size_t)M * K_DIM;

    ln_quant_kernel<<<M, 256, 0, stream>>>(x, ln_g, ln_b, gamma_p, xq);
    wtrans_kernel<<<dim3(N_DIM / 64, K_DIM / 64), 256, 0, stream>>>(w, wq);
    gemm_kernel<<<dim3(N_DIM / 256, M / 128), 256, 0, stream>>>(xq, wq, out, beta_p, gamma_p);
}

// Round 9
// 248.755 us; speedup vs baseline: 1.2341x; 1.2341x over previous
//
#include <hip/hip_runtime.h>

using f32x4  = __attribute__((ext_vector_type(4))) float;
using i32x4  = __attribute__((ext_vector_type(4))) int;
using i32x16 = __attribute__((ext_vector_type(16))) int;

constexpr int K_DIM = 4096;   // N_IN
constexpr int N_DIM = 4096;   // N_OUT
constexpr float QBf = 128.0f;
constexpr float EPf = 0.01f;
constexpr float LN_EPSf = 1e-5f;

#define GLOAD_LDS16(gp, lp)                                                  \
    __builtin_amdgcn_global_load_lds(                                        \
        (const __attribute__((address_space(1))) void*)(gp),                 \
        (__attribute__((address_space(3))) void*)(lp), 16, 0, 0)

#define BARRIER()                                                            \
    do { asm volatile("" ::: "memory");                                      \
         __builtin_amdgcn_s_barrier();                                       \
         asm volatile("" ::: "memory"); } while (0)

#define WAIT_LGKM(N)                                                         \
    do { asm volatile("s_waitcnt lgkmcnt(" #N ")" ::: "memory");             \
         __builtin_amdgcn_sched_barrier(0); } while (0)

// ---------------------------------------------------------------------------
// Kernel 1: fused LayerNorm + ABSMax-quant + round-to-int8.  One block/row.
// ---------------------------------------------------------------------------
__global__ __launch_bounds__(256) void ln_quant_kernel(
    const float* __restrict__ x,
    const float* __restrict__ ln_g,
    const float* __restrict__ ln_b,
    const float* __restrict__ gamma_p,
    char* __restrict__ xq)
{
    const int row = blockIdx.x;
    const int t = threadIdx.x;
    const float4* xr4 = reinterpret_cast<const float4*>(x + (size_t)row * K_DIM);

    float4 v[4];
    float sum = 0.f, sumsq = 0.f;
#pragma unroll
    for (int i = 0; i < 4; ++i) {
        v[i] = xr4[t * 4 + i];
        sum += v[i].x + v[i].y + v[i].z + v[i].w;
        sumsq += v[i].x * v[i].x + v[i].y * v[i].y + v[i].z * v[i].z + v[i].w * v[i].w;
    }
#pragma unroll
    for (int off = 32; off > 0; off >>= 1) {
        sum += __shfl_down(sum, off);
        sumsq += __shfl_down(sumsq, off);
    }
    __shared__ float s_sum[4], s_sq[4];
    const int lane = t & 63, w = t >> 6;
    if (lane == 0) { s_sum[w] = sum; s_sq[w] = sumsq; }
    __syncthreads();
    sum = s_sum[0] + s_sum[1] + s_sum[2] + s_sum[3];
    sumsq = s_sq[0] + s_sq[1] + s_sq[2] + s_sq[3];

    const float mu = sum * (1.0f / K_DIM);
    const float var = sumsq * (1.0f / K_DIM) - mu * mu;
    const float rstd = rsqrtf(var + LN_EPSf);
    const float qs = QBf / gamma_p[0];
    const float lo = -QBf + EPf, hi = QBf - EPf;

    alignas(16) char ob[16];
#pragma unroll
    for (int i = 0; i < 4; ++i) {
        const float4 g = reinterpret_cast<const float4*>(ln_g)[t * 4 + i];
        const float4 b = reinterpret_cast<const float4*>(ln_b)[t * 4 + i];
        const float f0 = fminf(fmaxf(((v[i].x - mu) * rstd * g.x + b.x) * qs, lo), hi);
        const float f1 = fminf(fmaxf(((v[i].y - mu) * rstd * g.y + b.y) * qs, lo), hi);
        const float f2 = fminf(fmaxf(((v[i].z - mu) * rstd * g.z + b.z) * qs, lo), hi);
        const float f3 = fminf(fmaxf(((v[i].w - mu) * rstd * g.w + b.w) * qs, lo), hi);
        int x0 = (int)rintf(f0), x1 = (int)rintf(f1);
        int x2 = (int)rintf(f2), x3 = (int)rintf(f3);
        ob[i * 4 + 0] = (char)(x0 > 127 ? 127 : x0);
        ob[i * 4 + 1] = (char)(x1 > 127 ? 127 : x1);
        ob[i * 4 + 2] = (char)(x2 > 127 ? 127 : x2);
        ob[i * 4 + 3] = (char)(x3 > 127 ? 127 : x3);
    }
    *reinterpret_cast<uint4*>(xq + (size_t)row * K_DIM + t * 16) =
        *reinterpret_cast<const uint4*>(ob);
}

// ---------------------------------------------------------------------------
// Kernel 2: w (fp32, K x N, values ±1) -> wq (int8, N x K).  64x64 tiles.
// ---------------------------------------------------------------------------
__global__ __launch_bounds__(256) void wtrans_kernel(
    const float* __restrict__ w, char* __restrict__ wq)
{
    __shared__ char tile[64][68];
    const int t = threadIdx.x;
    const int bk = blockIdx.y * 64;
    const int bn = blockIdx.x * 64;
#pragma unroll
    for (int i = 0; i < 4; ++i) {
        const int li = i * 1024 + t * 4;
        const int r = li >> 6, c = li & 63;    // r = k-in-tile, c = n-in-tile
        const float4 vv = *reinterpret_cast<const float4*>(
            w + (size_t)(bk + r) * N_DIM + bn + c);
        tile[r][c]     = (char)vv.x;
        tile[r][c + 1] = (char)vv.y;
        tile[r][c + 2] = (char)vv.z;
        tile[r][c + 3] = (char)vv.w;
    }
    __syncthreads();
    const int n = t >> 2, kc = t & 3;
    alignas(16) char h16[16];
#pragma unroll
    for (int j = 0; j < 16; ++j) h16[j] = tile[kc * 16 + j][n];
    *reinterpret_cast<uint4*>(wq + (size_t)(bn + n) * K_DIM + bk + kc * 16) =
        *reinterpret_cast<const uint4*>(h16);
}

// ---------------------------------------------------------------------------
// Kernel 3: GEMM  C[M,N] = A[M,K] * Bt[N,K]^T * scale  (i8 MFMA, i32 acc)
// 256x256 tile, BK=64, 512 threads = 8 waves (2M x 4N), wave tile 128x64
// (4 m-frags x 2 n-frags of mfma_i32_32x32x32_i8, 2 k-steps per K-tile).
// FOUR LDS buffers (4 x 32 KiB ring): tile t lives in buf t&3; stages issued
// at tile t target tile t+3 -> buf (t+3)&3 == buf(t-1), WAR-safe right after
// the end-of-tile-(t-1) barrier.  ONE barrier per K-tile (no mid-tile WAR
// barrier needed).  End-of-tile vmcnt(8) forces tile t+1's stages (issued
// 3 tiles back, ~2 tiles of MFMA cover) while leaving 8 loads in flight.
// LDS K-block layout [kc][row][16B]: frag reads are 512 contiguous bytes per
// 32-lane group -> zero bank conflicts, linear global_load_lds dest.
// Per K-tile (counted lgkm chain identical to R7):
//   R0: read bfrag x8 + afr(ks0,mf01) x2
//   s0: read afr(ks0,mf23) | STAGE A(t+3) | lgkm(2) | MFMA ks0,mf01
//   s1: read afr(ks1,mf01) |               lgkm(2) | MFMA ks0,mf23
//   s2: read afr(ks1,mf23) | STAGE B(t+3) | lgkm(2) | MFMA ks1,mf01
//   s3:                                    lgkm(0) | MFMA ks1,mf23
//       | vmcnt(8) | BARRIER
// ---------------------------------------------------------------------------
__global__ __launch_bounds__(512, 2) void gemm_kernel(
    const char* __restrict__ A,
    const char* __restrict__ Bt,
    float* __restrict__ C,
    const float* __restrict__ beta_p,
    const float* __restrict__ gamma_p)
{
    constexpr int NT = K_DIM / 64;                 // 64 K-tiles
    __shared__ __align__(16) char lds[131072];     // 4 bufs x (A 16K | B 16K)

    const int t = threadIdx.x;
    // ---- XCD swizzle: flat id -> 8x8 square per XCD (512 blocks, 16x32 grid)
    const int flat = blockIdx.y * gridDim.x + blockIdx.x;
    const int xcd = flat & 7;
    const int r8 = flat >> 3;                       // 0..63
    const int by = ((xcd >> 1) << 3) + (r8 >> 3);   // 0..31  (M index)
    const int bx = ((xcd & 1) << 3) + (r8 & 7);     // 0..15  (N index)
    const int bm = by * 256;
    const int bn = bx * 256;

    const int lane = t & 63;
    const int w = t >> 6;
    const int wm = w >> 2;            // 0..1
    const int wn = w & 3;             // 0..3
    const int ln31 = lane & 31;
    const int lg2 = lane >> 5;        // 0..1

    const char* gA = A + (size_t)bm * K_DIM;
    const char* gB = Bt + (size_t)bn * K_DIM;
    // per-lane staging source offset: row (t&127), k-chunk (t>>7)
    const int voff = (t & 127) * K_DIM + (t >> 7) * 16;

    // per-lane fragment read offsets within a 128-row half region
    const int aoff = lg2 * 2048 + ln31 * 16;
    const int boff = lg2 * 2048 + ((wn & 1) * 64 + ln31) * 16;

    // stage half-tile ht (0=Ah0,1=Ah1,2=Bh0,3=Bh1) of K-tile kt into buffer b
#define STAGE_HT(b, ht, kt)                                                   \
    GLOAD_LDS16((((ht) < 2) ? gA : gB)                                        \
                    + (size_t)(((ht) & 1) * (128 * K_DIM) + (kt) * 64) + voff,\
                lds + (b) * 32768 + (((ht) < 2) ? 0 : 16384)                  \
                    + ((ht) & 1) * 8192 + t * 16)

#define READ_A(par, ks, mfp)                                                  \
    do {                                                                      \
        afr[par][0] = *reinterpret_cast<const i32x4*>(                        \
            abase + (ks) * 4096 + ((mfp) * 2) * 512 + aoff);                  \
        afr[par][1] = *reinterpret_cast<const i32x4*>(                        \
            abase + (ks) * 4096 + ((mfp) * 2 + 1) * 512 + aoff);              \
    } while (0)

#define MFMA4(par, ks, mfp)                                                   \
    do {                                                                      \
        __builtin_amdgcn_s_setprio(1);                                        \
        _Pragma("unroll")                                                     \
        for (int m2 = 0; m2 < 2; ++m2)                                        \
            _Pragma("unroll")                                                 \
            for (int nf = 0; nf < 2; ++nf)                                    \
                acc[(mfp) * 2 + m2][nf] =                                     \
                    __builtin_amdgcn_mfma_i32_32x32x32_i8(                    \
                        afr[par][m2], bfrag[nf][ks],                          \
                        acc[(mfp) * 2 + m2][nf], 0, 0, 0);                    \
        __builtin_amdgcn_s_setprio(0);                                        \
    } while (0)

    i32x16 acc[4][2];
#pragma unroll
    for (int m = 0; m < 4; ++m)
#pragma unroll
        for (int n = 0; n < 2; ++n)
#pragma unroll
            for (int q = 0; q < 16; ++q)
                acc[m][n][q] = 0;

    // prologue: stage tiles 0,1,2 into bufs 0,1,2; force tile 0 landed; sync
    STAGE_HT(0, 0, 0); STAGE_HT(0, 1, 0); STAGE_HT(0, 2, 0); STAGE_HT(0, 3, 0);
    STAGE_HT(1, 0, 1); STAGE_HT(1, 1, 1); STAGE_HT(1, 2, 1); STAGE_HT(1, 3, 1);
    STAGE_HT(2, 0, 2); STAGE_HT(2, 1, 2); STAGE_HT(2, 2, 2); STAGE_HT(2, 3, 2);
    asm volatile("s_waitcnt vmcnt(8)" ::: "memory");
    BARRIER();

    for (int kt = 0; kt < NT; kt += 4) {
#pragma unroll
        for (int h = 0; h < 4; ++h) {
            const int tt = kt + h;                         // current K-tile
            const int sb = (h + 3) & 3;                    // stage buffer
            const char* abase = lds + h * 32768 + wm * 8192;
            const char* bbase = lds + h * 32768 + 16384 + (wn >> 1) * 8192;

            i32x4 bfrag[2][2];   // [nf][ks]
            i32x4 afr[2][2];     // [parity][m2]

            // ---- R0: all B frags + A frags (ks0, mf01) ----
#pragma unroll
            for (int nf = 0; nf < 2; ++nf)
#pragma unroll
                for (int ks = 0; ks < 2; ++ks)
                    bfrag[nf][ks] = *reinterpret_cast<const i32x4*>(
                        bbase + ks * 4096 + nf * 512 + boff);
            READ_A(0, 0, 0);

            // ---- s0 ----
            READ_A(1, 0, 1);
            if (tt + 3 < NT) { STAGE_HT(sb, 0, tt + 3); STAGE_HT(sb, 1, tt + 3); }
            WAIT_LGKM(2);
            MFMA4(0, 0, 0);

            // ---- s1 ----
            READ_A(0, 1, 0);
            WAIT_LGKM(2);
            MFMA4(1, 0, 1);

            // ---- s2 ----
            READ_A(1, 1, 1);
            if (tt + 3 < NT) { STAGE_HT(sb, 2, tt + 3); STAGE_HT(sb, 3, tt + 3); }
            WAIT_LGKM(2);
            MFMA4(0, 1, 0);

            // ---- s3 ----
            WAIT_LGKM(0);
            MFMA4(1, 1, 1);
            asm volatile("s_waitcnt vmcnt(8)" ::: "memory");
            BARRIER();                    // tile tt+1 fully staged; buf(tt)
                                          // reads done -> reusable next tile
        }
    }

    // ---- epilogue: 32x32 C/D layout: col=lane&31,
    //      row = (reg&3) + 8*(reg>>2) + 4*(lane>>5) ----
    const float scale = beta_p[0] * gamma_p[0] * (1.0f / QBf);
    const int orow0 = bm + wm * 128 + lg2 * 4;
    const int ocol0 = bn + wn * 64 + ln31;
#pragma unroll
    for (int mf = 0; mf < 4; ++mf) {
#pragma unroll
        for (int nf = 0; nf < 2; ++nf) {
#pragma unroll
            for (int reg = 0; reg < 16; ++reg) {
                const int row = orow0 + mf * 32 + (reg & 3) + 8 * (reg >> 2);
                C[(size_t)row * N_DIM + ocol0 + nf * 32] =
                    (float)acc[mf][nf][reg] * scale;
            }
        }
    }
#undef STAGE_HT
#undef READ_A
#undef MFMA4
}

// ---------------------------------------------------------------------------
extern "C" void kernel_launch(void* const* d_in, const int* in_sizes, int n_in,
                              void* d_out, int out_size, void* d_ws, size_t ws_size,
                              hipStream_t stream)
{
    const float* x       = (const float*)d_in[0];
    const float* w       = (const float*)d_in[1];
    const float* ln_g    = (const float*)d_in[2];
    const float* ln_b    = (const float*)d_in[3];
    const float* beta_p  = (const float*)d_in[4];
    const float* gamma_p = (const float*)d_in[5];
    float* out = (float*)d_out;

    const int M = in_sizes[0] / K_DIM;   // 8192

    char* xq = (char*)d_ws;
    char* wq = (char*)d_ws + (size_t)M * K_DIM;

    ln_quant_kernel<<<M, 256, 0, stream>>>(x, ln_g, ln_b, gamma_p, xq);
    wtrans_kernel<<<dim3(N_DIM / 64, K_DIM / 64), 256, 0, stream>>>(w, wq);
    gemm_kernel<<<dim3(N_DIM / 256, M / 256), 512, 0, stream>>>(xq, wq, out, beta_p, gamma_p);
}